// Round 6
// baseline (502.969 us; speedup 1.0000x reference)
//
#include <hip/hip_runtime.h>

typedef unsigned short u16;
typedef __attribute__((ext_vector_type(8))) short short8;   // 8 bf16 = 4 VGPRs (MFMA A/B frag)
typedef __attribute__((ext_vector_type(4))) float f32x4;    // MFMA C/D frag

#define T_SEQ 8192
#define DDIM 1024
#define BB 4
#define MM (BB * T_SEQ)      // 32768
#define NC 128               // chunks along T
#define CHUNK (T_SEQ / NC)   // 64
#define CHAINS (BB * DDIM)   // 4096

// ---------- helpers ----------
__device__ __forceinline__ float bf_lo(unsigned p) {
    union { unsigned u; float f; } v; v.u = p << 16; return v.f;
}
__device__ __forceinline__ float bf_hi(unsigned p) {
    union { unsigned u; float f; } v; v.u = p & 0xffff0000u; return v.f;
}
__device__ __forceinline__ float bf_u16(u16 p) {
    union { unsigned u; float f; } v; v.u = ((unsigned)p) << 16; return v.f;
}
__device__ __forceinline__ u16 f2bf(float f) {
    union { unsigned u; float f; } v; v.f = f;
    unsigned r = v.u + 0x7fffu + ((v.u >> 16) & 1u);   // RNE
    return (u16)(r >> 16);
}
__device__ __forceinline__ float sigm(float z) {
    return __builtin_amdgcn_rcpf(1.0f + __expf(-z));
}
__device__ __forceinline__ void gld16(const u16* g, u16* l) {
    __builtin_amdgcn_global_load_lds((const __attribute__((address_space(1))) void*)g,
                                     (__attribute__((address_space(3))) void*)l, 16, 0, 0);
}

// ---------- K1: fused fp32 -> bf16 convert for x, W_in, W_gate ----------
#define N4X (MM * DDIM / 4)      // 8388608 float4s
#define N4W (DDIM * DDIM / 4)    // 262144 float4s
__global__ __launch_bounds__(256) void cvt_all(const float* __restrict__ x,
                                               const float* __restrict__ Wi,
                                               const float* __restrict__ Wg,
                                               u16* __restrict__ Xb,
                                               u16* __restrict__ Wib,
                                               u16* __restrict__ Wgb) {
    int i = blockIdx.x * 256 + threadIdx.x;   // global float4 index
    const float* src; u16* dst; int j;
    if (i < N4X)            { src = x;  dst = Xb;  j = i; }
    else if (i < N4X + N4W) { src = Wi; dst = Wib; j = i - N4X; }
    else                    { src = Wg; dst = Wgb; j = i - N4X - N4W; }
    float4 v = ((const float4*)src)[j];
    ushort4 o;
    o.x = f2bf(v.x); o.y = f2bf(v.y); o.z = f2bf(v.z); o.w = f2bf(v.w);
    ((ushort4*)dst)[j] = o;
}

// ---------- K2: fused bf16 GEMM + gating epilogue (FAT-WAVE geometry) ----------
// R2-R5 post-mortem: 8x(128x64) waves give per-K32 LDS demand (96KB reads +
// 32KB stage-writes ~ 1450 cyc/CU) EXCEEDING the MFMA window (1240 cyc/SIMD)
// -> any bubble serializes -> 30-33% MfmaUtil for FOUR different schedules.
// Fix the RATIO: 4 waves x (128x128) on the same 256x256 virtual tile
// (wn = gate). Reads/wave/K32 = 8A+8B = 16KB for 64 MFMA (0.25 vs 0.375
// reads/MFMA). Per-CU LDS = 64KB (~750cyc) vs MFMA 2480 cyc/SIMD -> 3.3x
// headroom: LDS hides under MFMA even with imperfect overlap. 1 wave/SIMD
// (acc 256 + frags 96 VGPRs, launch_bounds(256,1)); a single wave issuing
// independent MFMAs back-to-back saturates the matrix pipe.
// Ring-4 LDS slots (unchanged 128KB layout), reg-pipelined frags (A0/A1
// phase ping-pong, B0/B1 pair parity), ONE vmcnt + ONE barrier per pair.
// 8 staging rounds/slot (4A + 4B covering both gates): steady vmcnt(8)
// certifies slot h+1 (outstanding = slots h+1,h+2 = 16 rounds).

#define MROW8(ri, af, bs)                                                                \
    acc[ri][0] = __builtin_amdgcn_mfma_f32_16x16x32_bf16(af, bs[0], acc[ri][0], 0,0,0);  \
    acc[ri][1] = __builtin_amdgcn_mfma_f32_16x16x32_bf16(af, bs[1], acc[ri][1], 0,0,0);  \
    acc[ri][2] = __builtin_amdgcn_mfma_f32_16x16x32_bf16(af, bs[2], acc[ri][2], 0,0,0);  \
    acc[ri][3] = __builtin_amdgcn_mfma_f32_16x16x32_bf16(af, bs[3], acc[ri][3], 0,0,0);  \
    acc[ri][4] = __builtin_amdgcn_mfma_f32_16x16x32_bf16(af, bs[4], acc[ri][4], 0,0,0);  \
    acc[ri][5] = __builtin_amdgcn_mfma_f32_16x16x32_bf16(af, bs[5], acc[ri][5], 0,0,0);  \
    acc[ri][6] = __builtin_amdgcn_mfma_f32_16x16x32_bf16(af, bs[6], acc[ri][6], 0,0,0);  \
    acc[ri][7] = __builtin_amdgcn_mfma_f32_16x16x32_bf16(af, bs[7], acc[ri][7], 0,0,0);

#define MQUAD(b_, aset, bset) MROW8((b_)+0, aset[0], bset) MROW8((b_)+1, aset[1], bset) \
                              MROW8((b_)+2, aset[2], bset) MROW8((b_)+3, aset[3], bset)

// reads (swizzled) from compile-time ring slot s_ (A slot 256rows x 32, B same)
#define LDA_S(s_, i) (*(const short8*)&lds[(s_)*8192 + (arow0 + (i)*16)*32 + aoff])
#define LDB_S(s_, j) (*(const short8*)&lds[32768 + (s_)*8192 + (brow0 + (j)*16)*32 + aoff])

#define RD_A(dst, s_, base) { dst[0] = LDA_S(s_, (base)+0); dst[1] = LDA_S(s_, (base)+1); \
                              dst[2] = LDA_S(s_, (base)+2); dst[3] = LDA_S(s_, (base)+3); }
#define RD_B8(dst, s_)      { dst[0] = LDB_S(s_, 0); dst[1] = LDB_S(s_, 1);               \
                              dst[2] = LDB_S(s_, 2); dst[3] = LDB_S(s_, 3);               \
                              dst[4] = LDB_S(s_, 4); dst[5] = LDB_S(s_, 5);               \
                              dst[6] = LDB_S(s_, 6); dst[7] = LDB_S(s_, 7); }

// staging: 4 rounds of 64 rows each for A and B (B vrows 0-127 Wi, 128-255 Wg)
#define STA_S(ds_, ht_, rb) gld16(gA + (size_t)(ht_)*32 + (size_t)(rb)*64*DDIM,          \
                                  &lds[(ds_)*8192 + (rb)*2048 + tid*8])
#define STB_S(ds_, ht_, rb) gld16(((rb) < 2 ? gBi + (size_t)(rb)*64*DDIM                 \
                                            : gBg + (size_t)((rb)-2)*64*DDIM)            \
                                      + (size_t)(ht_)*32,                                \
                                  &lds[32768 + (ds_)*8192 + (rb)*2048 + tid*8])
#define ST8(ds_, ht_) STA_S(ds_, ht_, 0); STA_S(ds_, ht_, 1); STA_S(ds_, ht_, 2);        \
                      STA_S(ds_, ht_, 3); STB_S(ds_, ht_, 0); STB_S(ds_, ht_, 1);        \
                      STB_S(ds_, ht_, 2); STB_S(ds_, ht_, 3);

// pair h: s_=h&3, sn_=(h+1)&3, ds_=(h+3)&3; BCUR=B(h&1), BNXT=B(1-(h&1))
#define PAIR_(s_, sn_, ds_, ht_, BCUR, BNXT, DOST, VMS, DORD)                          \
    RD_A(A1, s_, 4)                               /* own rows 4-7 (slot certified) */  \
    __builtin_amdgcn_s_setprio(1);                                                     \
    MQUAD(0, A0, BCUR)                            /* 32 MFMA */                        \
    __builtin_amdgcn_s_setprio(0);                                                     \
    asm volatile("s_waitcnt " VMS ::: "memory");  /* certify slot sn_ */               \
    __builtin_amdgcn_s_barrier();                                                      \
    if (DORD) { RD_B8(BNXT, sn_) RD_A(A0, sn_, 0) }  /* 12 reads for pair h+1 */       \
    if (DOST) { ST8(ds_, ht_) }                      /* stage half-tile h+3 */         \
    __builtin_amdgcn_s_setprio(1);                                                     \
    MQUAD(4, A1, BCUR)                            /* 32 MFMA */                        \
    __builtin_amdgcn_s_setprio(0);

__global__ __launch_bounds__(256, 1)
void gemm_fused(const u16* __restrict__ X, const u16* __restrict__ Wi,
                const u16* __restrict__ Wg, const float* __restrict__ b_in,
                const float* __restrict__ b_gate, const float* __restrict__ lam,
                u16* __restrict__ Sg, u16* __restrict__ XBg) {
    const int bid = blockIdx.x;         // 0..1023
    const int xcd = bid & 7;
    const int r = bid >> 3;             // 0..127
    const int n_tile = r & 7;           // N fastest within an XCD
    const int m_tile = xcd * 16 + (r >> 3);
    const int tN0 = n_tile * 128;
    const int tM0 = m_tile * 256;

    const int tid = threadIdx.x;        // 0..255
    const int lane = tid & 63;
    const int w = tid >> 6;             // 0..3
    const int wm = w >> 1;              // 0..1 (M half)
    const int gate = w & 1;             // 0: IG (Wi), 1: RG (Wg)

    __shared__ u16 lds[65536];          // 128KB: A ring [0,32768), B ring [32768,65536)

    // staging source pointers (per-thread, pre-swizzled column chunk)
    const int srow = tid >> 2;                          // 0..63
    const int c8log = (tid & 3) ^ ((tid >> 3) & 3);     // inverse swizzle on source
    const u16* gA  = X  + (size_t)(tM0 + srow) * DDIM + c8log * 8;
    const u16* gBi = Wi + (size_t)(tN0 + srow) * DDIM + c8log * 8;
    const u16* gBg = Wg + (size_t)(tN0 + srow) * DDIM + c8log * 8;

    // read-side constants
    const int lm = lane & 15;
    const int aoff = (((lane >> 4) ^ ((lm >> 1) & 3))) * 8;  // swizzled chunk, lane-only
    const int arow0 = wm * 128 + lm;                 // + i*16, i 0..7
    const int brow0 = gate * 128 + lm;               // + j*16, j 0..7

    f32x4 acc[8][8] = {};
    short8 A0[4], A1[4], B0[8], B1[8];

    // ---- prologue: stage slots 0,1,2 (24 rounds); certify slot 0; preload pair 0 ----
    ST8(0, 0) ST8(1, 1) ST8(2, 2)
    asm volatile("s_waitcnt vmcnt(16)" ::: "memory");   // slot 0 landed
    __builtin_amdgcn_s_barrier();
    RD_B8(B0, 0) RD_A(A0, 0, 0)

    // ---- main loop: pairs 0..27 (ring-unrolled x4); pair h stages h+3 ----
    for (int g = 0; g < 7; ++g) {
        const int hb = 4 * g;
        PAIR_(0, 1, 3, hb + 3, B0, B1, 1, "vmcnt(8)", 1)
        PAIR_(1, 2, 0, hb + 4, B1, B0, 1, "vmcnt(8)", 1)
        PAIR_(2, 3, 1, hb + 5, B0, B1, 1, "vmcnt(8)", 1)
        PAIR_(3, 0, 2, hb + 6, B1, B0, 1, "vmcnt(8)", 1)
    }
    // ---- tail: pair 28 stages 31; drains 8 -> 0; pair 31 computes only ----
    PAIR_(0, 1, 3, 31, B0, B1, 1, "vmcnt(8)", 1)
    PAIR_(1, 2, 0, 0,  B1, B0, 0, "vmcnt(8)", 1)
    PAIR_(2, 3, 0, 0,  B0, B1, 0, "vmcnt(0)", 1)
    PAIR_(3, 0, 0, 0,  B1, B0, 0, "vmcnt(0)", 0)
    asm volatile("s_waitcnt lgkmcnt(0)" ::: "memory");
    __builtin_amdgcn_s_barrier();        // all LDS reads done -> safe to reuse

    // ---- epilogue stage 1: dump per-acc values to LDS (XOR bank swizzle) ----
    // C/D layout: col=lane&15, row=(lane>>4)*4+rr. Per-wave 128x128 quarter.
    // S region  lds[0,32768):      s  (bf16, == value the scan consumes)
    // P region  lds[32768,65536):  p  (u16 fixed-point /65535 -> err ~1e-5)
    const int r0 = (lane >> 4) << 2;
    const int cb = lane & 15;
    if (gate) {                          // RG wave: s = nsp*sigm(rg+b)
#pragma unroll
        for (int j = 0; j < 8; ++j) {
            const int colg = tN0 + j * 16 + cb;
            const int cl = j * 16 + cb;
            const float bj = b_gate[colg];
            const float nsp = -8.0f * log1pf(__expf(lam[colg]));
#pragma unroll
            for (int i = 0; i < 8; ++i) {
                const int rl0 = wm * 128 + i * 16 + r0;
#pragma unroll
                for (int rr = 0; rr < 4; ++rr) {
                    const int rl = rl0 + rr;
                    float s = nsp * sigm(acc[i][j][rr] + bj);
                    lds[rl * 128 + (cl ^ (((rl >> 2) & 7) << 4))] = f2bf(s);
                }
            }
        }
    } else {                             // IG wave: p = sigm(ig+b), fixed-point
#pragma unroll
        for (int j = 0; j < 8; ++j) {
            const int colg = tN0 + j * 16 + cb;
            const int cl = j * 16 + cb;
            const float bj = b_in[colg];
#pragma unroll
            for (int i = 0; i < 8; ++i) {
                const int rl0 = wm * 128 + i * 16 + r0;
#pragma unroll
                for (int rr = 0; rr < 4; ++rr) {
                    const int rl = rl0 + rr;
                    float p = sigm(acc[i][j][rr] + bj);
                    lds[32768 + rl * 128 + (cl ^ (((rl >> 2) & 7) << 4))] =
                        (u16)(p * 65535.0f + 0.5f);
                }
            }
        }
    }
    asm volatile("s_waitcnt lgkmcnt(0)" ::: "memory");
    __builtin_amdgcn_s_barrier();
    __builtin_amdgcn_sched_barrier(0);

    // ---- epilogue stage 2: vectorized combine + 16B stores ----
    // thread -> col-chunk cc (8 cols), rows rbase..rbase+15 (full 256x128 tile)
    const int cc = tid & 15;
    const int rbase = (tid >> 4) * 16;
#pragma unroll
    for (int k = 0; k < 16; ++k) {
        const int rl = rbase + k;
        const int ch = (cc ^ (((rl >> 2) & 7) << 1)) * 8;   // swizzled chunk base
        short8 sv = *(const short8*)&lds[rl * 128 + ch];
        short8 pv = *(const short8*)&lds[32768 + rl * 128 + ch];
        const size_t go = (size_t)(tM0 + rl) * DDIM + tN0 + cc * 8;
        short8 xv = *(const short8*)&X[go];
        short8 ov;
#pragma unroll
        for (int e = 0; e < 8; ++e) {
            float s = bf_u16((u16)sv[e]);
            float p = (float)((u16)pv[e]) * (1.0f / 65535.0f);
            float xf = bf_u16((u16)xv[e]);
            float be = sqrtf(1.0f - __expf(2.0f * s) + 1e-6f);
            ov[e] = (short)f2bf(be * p * xf);
        }
        *(short8*)&Sg[go] = sv;
        *(short8*)&XBg[go] = ov;
    }
}

// ---------- K3: pass1 — per-chunk aggregates (light: 1 exp + 2 fma / elem) ----------
__global__ __launch_bounds__(256)
void scan_pass1(const u16* __restrict__ S, const u16* __restrict__ XB,
                float* __restrict__ AggA, float* __restrict__ AggB) {
    const int c = blockIdx.x, dblk = blockIdx.y, bq = blockIdx.z;
    const int d0 = dblk * 512 + threadIdx.x * 2;
    size_t base = ((size_t)(bq * T_SEQ + c * CHUNK)) * DDIM + d0;

    float A0 = 1.0f, B0 = 0.0f, A1 = 1.0f, B1 = 0.0f;
#pragma unroll 8
    for (int t = 0; t < CHUNK; t++) {
        unsigned sp = *(const unsigned*)(S + base);
        unsigned xp = *(const unsigned*)(XB + base);
        float a0 = __expf(bf_lo(sp));
        float a1 = __expf(bf_hi(sp));
        B0 = fmaf(a0, B0, bf_lo(xp)); A0 *= a0;
        B1 = fmaf(a1, B1, bf_hi(xp)); A1 *= a1;
        base += DDIM;
    }
    const int chain = bq * DDIM + d0;
    float2 av; av.x = A0; av.y = A1;
    float2 bv; bv.x = B0; bv.y = B1;
    *(float2*)(AggA + (size_t)c * CHAINS + chain) = av;
    *(float2*)(AggB + (size_t)c * CHAINS + chain) = bv;
}

// ---------- K4: pass2 — serial scan over NC chunk aggregates per chain ----------
__global__ __launch_bounds__(256)
void scan_pass2(const float* __restrict__ AggA, const float* __restrict__ AggB,
                float* __restrict__ H0) {
    const int chain = blockIdx.x * 256 + threadIdx.x;   // 4096 chains
    float p = 0.0f;
#pragma unroll 8
    for (int c = 0; c < NC; c++) {
        H0[(size_t)c * CHAINS + chain] = p;
        p = AggA[(size_t)c * CHAINS + chain] * p + AggB[(size_t)c * CHAINS + chain];
    }
}

// ---------- K5: pass3 — apply chunk prefix, write h ----------
__global__ __launch_bounds__(256)
void scan_pass3(const u16* __restrict__ S, const u16* __restrict__ XB,
                const float* __restrict__ H0, float* __restrict__ out) {
    const int c = blockIdx.x, dblk = blockIdx.y, bq = blockIdx.z;
    const int d0 = dblk * 512 + threadIdx.x * 2;
    size_t base = ((size_t)(bq * T_SEQ + c * CHUNK)) * DDIM + d0;
    const int chain = bq * DDIM + d0;

    float2 h = *(const float2*)(H0 + (size_t)c * CHAINS + chain);
#pragma unroll 8
    for (int t = 0; t < CHUNK; t++) {
        unsigned sp = *(const unsigned*)(S + base);
        unsigned xp = *(const unsigned*)(XB + base);
        float a0 = __expf(bf_lo(sp));
        float a1 = __expf(bf_hi(sp));
        h.x = fmaf(a0, h.x, bf_lo(xp));
        h.y = fmaf(a1, h.y, bf_hi(xp));
        *(float2*)(out + base) = h;
        base += DDIM;
    }
}

// ---------- launch ----------
extern "C" void kernel_launch(void* const* d_in, const int* in_sizes, int n_in,
                              void* d_out, int out_size, void* d_ws, size_t ws_size,
                              hipStream_t stream) {
    const float* x   = (const float*)d_in[0];
    const float* Win = (const float*)d_in[1];
    const float* bin = (const float*)d_in[2];
    const float* Wg  = (const float*)d_in[3];
    const float* bg  = (const float*)d_in[4];
    const float* lam = (const float*)d_in[5];
    float* out = (float*)d_out;

    // ws layout (MiB): Wi_bf 0..2, Wg_bf 2..4, S 4..68, XB 68..132,
    // AggA 132..134, AggB 134..136, H0 136..138  (= 138 MiB)
    char* w = (char*)d_ws;
    u16* Wi_bf  = (u16*)(w);
    u16* Wg_bf  = (u16*)(w + (size_t)(2) * 1024 * 1024);
    u16* Sg     = (u16*)(w + (size_t)(4) * 1024 * 1024);
    u16* XBg    = (u16*)(w + (size_t)(68) * 1024 * 1024);
    float* AggA = (float*)(w + (size_t)(132) * 1024 * 1024);
    float* AggB = (float*)(w + (size_t)(134) * 1024 * 1024);
    float* H0   = (float*)(w + (size_t)(136) * 1024 * 1024);

    // x_bf16 staged in first 64 MiB of d_out (read by GEMM main loop AND
    // epilogue; dead after GEMM; pass3 then overwrites d_out with h)
    u16* Xbf = (u16*)d_out;

    // K1: one fused convert (x + both W)
    cvt_all<<<dim3((N4X + 2 * N4W) / 256), dim3(256), 0, stream>>>(
        x, Win, Wg, Xbf, Wi_bf, Wg_bf);

    // K2: fused gate GEMM + gating epilogue, fat-wave (4x 128x128) geometry
    gemm_fused<<<dim3((DDIM / 128) * (MM / 256)), dim3(256), 0, stream>>>(
        Xbf, Wi_bf, Wg_bf, bin, bg, lam, Sg, XBg);

    // K3-K5: chunked scan over compact bf16 (S, XB)
    scan_pass1<<<dim3(NC, 2, BB), dim3(256), 0, stream>>>(Sg, XBg, AggA, AggB);
    scan_pass2<<<dim3(CHAINS / 256), dim3(256), 0, stream>>>(AggA, AggB, H0);
    scan_pass3<<<dim3(NC, 2, BB), dim3(256), 0, stream>>>(Sg, XBg, H0, out);
}

// Round 7
// 461.517 us; speedup vs baseline: 1.0898x; 1.0898x over previous
//
#include <hip/hip_runtime.h>

typedef unsigned short u16;
typedef __attribute__((ext_vector_type(8))) short short8;   // 8 bf16 = 4 VGPRs (MFMA A/B frag)
typedef __attribute__((ext_vector_type(4))) float f32x4;    // MFMA C/D frag

#define T_SEQ 8192
#define DDIM 1024
#define BB 4
#define MM (BB * T_SEQ)      // 32768
#define NC 128               // chunks along T
#define CHUNK (T_SEQ / NC)   // 64
#define CHAINS (BB * DDIM)   // 4096

// ---------- helpers ----------
__device__ __forceinline__ float bf_lo(unsigned p) {
    union { unsigned u; float f; } v; v.u = p << 16; return v.f;
}
__device__ __forceinline__ float bf_hi(unsigned p) {
    union { unsigned u; float f; } v; v.u = p & 0xffff0000u; return v.f;
}
__device__ __forceinline__ float bf_u16(u16 p) {
    union { unsigned u; float f; } v; v.u = ((unsigned)p) << 16; return v.f;
}
__device__ __forceinline__ u16 f2bf(float f) {
    union { unsigned u; float f; } v; v.f = f;
    unsigned r = v.u + 0x7fffu + ((v.u >> 16) & 1u);   // RNE
    return (u16)(r >> 16);
}
__device__ __forceinline__ float sigm(float z) {
    return __builtin_amdgcn_rcpf(1.0f + __expf(-z));
}
__device__ __forceinline__ void gld16(const u16* g, u16* l) {
    __builtin_amdgcn_global_load_lds((const __attribute__((address_space(1))) void*)g,
                                     (__attribute__((address_space(3))) void*)l, 16, 0, 0);
}

// ---------- K1: fused fp32 -> bf16 convert for x, W_in, W_gate ----------
#define N4X (MM * DDIM / 4)      // 8388608 float4s
#define N4W (DDIM * DDIM / 4)    // 262144 float4s
__global__ __launch_bounds__(256) void cvt_all(const float* __restrict__ x,
                                               const float* __restrict__ Wi,
                                               const float* __restrict__ Wg,
                                               u16* __restrict__ Xb,
                                               u16* __restrict__ Wib,
                                               u16* __restrict__ Wgb) {
    int i = blockIdx.x * 256 + threadIdx.x;   // global float4 index
    const float* src; u16* dst; int j;
    if (i < N4X)            { src = x;  dst = Xb;  j = i; }
    else if (i < N4X + N4W) { src = Wi; dst = Wib; j = i - N4X; }
    else                    { src = Wg; dst = Wgb; j = i - N4X - N4W; }
    float4 v = ((const float4*)src)[j];
    ushort4 o;
    o.x = f2bf(v.x); o.y = f2bf(v.y); o.z = f2bf(v.z); o.w = f2bf(v.w);
    ((ushort4*)dst)[j] = o;
}

// ---------- K2: fused bf16 GEMM + gating epilogue + FUSED scan_pass1 ----------
// Main loop: Round-4's best measured config (183.4 us, MfmaUtil 33%, VGPR 108):
// 8 waves (2M x 4N), 256x256 virtual tile, ring-4 LDS slots, two 16-MFMA
// phases per K=32 half-tile, vmcnt cert one pair ahead, never 0 mid-loop.
// NEW (R6 post-mortem): the epilogue's stage 2 already holds the full
// 256x128 S/XB tile -> the 256 M-rows are exactly 4 aligned chunks of 64 ->
// compute scan_pass1's per-chunk (A = prod alpha, B = scan of xb) here from
// the SAME quantized values (bf16 s, bf16 xb) pass1 would have read, and
// delete the pass1 kernel (132 MiB of HBM traffic + a launch).

#define MROW(i_, av)                                                                   \
    acc[i_][0] = __builtin_amdgcn_mfma_f32_16x16x32_bf16(av, b0, acc[i_][0], 0, 0, 0); \
    acc[i_][1] = __builtin_amdgcn_mfma_f32_16x16x32_bf16(av, b1, acc[i_][1], 0, 0, 0); \
    acc[i_][2] = __builtin_amdgcn_mfma_f32_16x16x32_bf16(av, b2, acc[i_][2], 0, 0, 0); \
    acc[i_][3] = __builtin_amdgcn_mfma_f32_16x16x32_bf16(av, b3, acc[i_][3], 0, 0, 0);

// reads (swizzled) from compile-time ring slot s_
#define LDA_S(s_, i) (*(const short8*)&lds[(s_)*8192 + (arow0 + (i)*16)*32 + aoff])
#define LDB_S(s_, j) (*(const short8*)&lds[32768 + (s_)*8192 + (brow0 + (j)*16)*32 + aoff])

// staging rounds into compile-time slot ds_, from half-tile index ht_ (runtime OK)
#define STA_S(ds_, ht_, rb) gld16(gA + (size_t)(ht_)*32 + (size_t)(rb)*128*DDIM,       \
                                  &lds[(ds_)*8192 + (rb)*4096 + tid*8])
#define STB_S(ds_, ht_, hf) gld16(((hf) ? gBg : gBi) + (size_t)(ht_)*32,               \
                                  &lds[32768 + (ds_)*8192 + (hf)*4096 + tid*8])

#define PHASE_A(s_, ds_, ht_, DOST)                                                    \
    b0 = LDB_S(s_, 0); b1 = LDB_S(s_, 1); b2 = LDB_S(s_, 2); b3 = LDB_S(s_, 3);        \
    a0 = LDA_S(s_, 0); a1 = LDA_S(s_, 1); a2 = LDA_S(s_, 2); a3 = LDA_S(s_, 3);        \
    if (DOST) { STA_S(ds_, ht_, 0); STA_S(ds_, ht_, 1); }                              \
    __builtin_amdgcn_s_barrier();                                                      \
    asm volatile("s_waitcnt lgkmcnt(0)" ::: "memory");                                 \
    __builtin_amdgcn_sched_barrier(0);                                                 \
    __builtin_amdgcn_s_setprio(1);                                                     \
    MROW(0, a0) MROW(1, a1) MROW(2, a2) MROW(3, a3)                                    \
    __builtin_amdgcn_s_setprio(0);                                                     \
    __builtin_amdgcn_s_barrier();

#define PHASE_B(s_, ds_, ht_, DOST, VMS)                                               \
    a0 = LDA_S(s_, 4); a1 = LDA_S(s_, 5); a2 = LDA_S(s_, 6); a3 = LDA_S(s_, 7);        \
    if (DOST) { STB_S(ds_, ht_, 0); STB_S(ds_, ht_, 1); }                              \
    asm volatile("s_waitcnt " VMS ::: "memory");                                       \
    __builtin_amdgcn_s_barrier();                                                      \
    asm volatile("s_waitcnt lgkmcnt(0)" ::: "memory");                                 \
    __builtin_amdgcn_sched_barrier(0);                                                 \
    __builtin_amdgcn_s_setprio(1);                                                     \
    MROW(4, a0) MROW(5, a1) MROW(6, a2) MROW(7, a3)                                    \
    __builtin_amdgcn_s_setprio(0);                                                     \
    __builtin_amdgcn_s_barrier();

#define PAIR(s_, ds_, ht_, DOST, VMS)                                                  \
    PHASE_A(s_, ds_, ht_, DOST)                                                        \
    PHASE_B(s_, ds_, ht_, DOST, VMS)

__global__ __launch_bounds__(512, 2)
void gemm_fused(const u16* __restrict__ X, const u16* __restrict__ Wi,
                const u16* __restrict__ Wg, const float* __restrict__ b_in,
                const float* __restrict__ b_gate, const float* __restrict__ lam,
                u16* __restrict__ Sg, u16* __restrict__ XBg,
                float* __restrict__ AggA, float* __restrict__ AggB) {
    const int bid = blockIdx.x;         // 0..1023
    const int xcd = bid & 7;
    const int r = bid >> 3;             // 0..127
    const int n_tile = r & 7;           // N fastest within an XCD
    const int m_tile = xcd * 16 + (r >> 3);
    const int tN0 = n_tile * 128;
    const int tM0 = m_tile * 256;

    const int tid = threadIdx.x;
    const int lane = tid & 63;
    const int w = tid >> 6;             // 0..7
    const int wm = w >> 2;              // 0..1 (M half)
    const int wn = w & 3;               // 0..3
    const int gate = wn >> 1;           // 0: IG, 1: RG
    const int wn_sub = wn & 1;

    __shared__ u16 lds[65536];          // 128KB: A ring [0,32768), B ring [32768,65536)

    // staging source pointers (per-thread, pre-swizzled column chunk)
    const int srow = tid >> 2;                          // 0..127
    const int c8log = (tid & 3) ^ ((tid >> 3) & 3);     // inverse swizzle on source
    const u16* gA  = X  + (size_t)(tM0 + srow) * DDIM + c8log * 8;
    const u16* gBi = Wi + (size_t)(tN0 + srow) * DDIM + c8log * 8;
    const u16* gBg = Wg + (size_t)(tN0 + srow) * DDIM + c8log * 8;

    // read-side constants
    const int lm = lane & 15;
    const int aoff = (((lane >> 4) ^ ((lm >> 1) & 3))) * 8;  // swizzled chunk, lane-only
    const int arow0 = wm * 128 + lm;                 // + i*16
    const int brow0 = gate * 128 + wn_sub * 64 + lm; // + j*16

    f32x4 acc[8][4] = {};
    short8 a0, a1, a2, a3, b0, b1, b2, b3;

    // ---- prologue: stage half-tiles 0,1,2 (12 rounds), certify slot 0 ----
    STA_S(0, 0, 0); STA_S(0, 0, 1); STB_S(0, 0, 0); STB_S(0, 0, 1);
    STA_S(1, 1, 0); STA_S(1, 1, 1); STB_S(1, 1, 0); STB_S(1, 1, 1);
    STA_S(2, 2, 0); STA_S(2, 2, 1); STB_S(2, 2, 0); STB_S(2, 2, 1);
    asm volatile("s_waitcnt vmcnt(8)" ::: "memory");   // slot 0 landed
    __builtin_amdgcn_s_barrier();

    // ---- main loop: pairs h = 4g..4g+3, stage h+3, certify h+1 ----
    for (int g = 0; g < 7; ++g) {
        const int hb = 4 * g;
        PAIR(0, 3, hb + 3, 1, "vmcnt(8)")
        PAIR(1, 0, hb + 4, 1, "vmcnt(8)")
        PAIR(2, 1, hb + 5, 1, "vmcnt(8)")
        PAIR(3, 2, hb + 6, 1, "vmcnt(8)")
    }
    // ---- tail: h = 28 (stage 31, cert 29), 29 (cert 30), 30 (cert 31), 31 ----
    PAIR(0, 3, 31, 1, "vmcnt(8)")
    PAIR(1, 0, 0, 0, "vmcnt(4)")
    PAIR(2, 0, 0, 0, "vmcnt(0)")
    PAIR(3, 0, 0, 0, "vmcnt(0)")
    // PHASE_B ends with a barrier: all slot reads drained -> LDS reusable

    // ---- epilogue stage 1: dump per-acc values to LDS (XOR bank swizzle) ----
    // C/D layout: col=lane&15, row=(lane>>4)*4+rr. Local tile 256x128.
    // S region  lds[0,32768):      s  (bf16, == value the scan consumes)
    // P region  lds[32768,65536):  p  (u16 fixed-point /65535 -> err ~1e-5)
    const int r0 = (lane >> 4) << 2;
    const int cb = lane & 15;
    if (gate) {                          // RG waves: s = nsp*sigm(rg+b)
#pragma unroll
        for (int j = 0; j < 4; ++j) {
            const int colg = tN0 + wn_sub * 64 + j * 16 + cb;
            const int cl = wn_sub * 64 + j * 16 + cb;
            const float bj = b_gate[colg];
            const float nsp = -8.0f * log1pf(__expf(lam[colg]));
#pragma unroll
            for (int i = 0; i < 8; ++i) {
                const int rl0 = wm * 128 + i * 16 + r0;
#pragma unroll
                for (int rr = 0; rr < 4; ++rr) {
                    const int rl = rl0 + rr;
                    float s = nsp * sigm(acc[i][j][rr] + bj);
                    lds[rl * 128 + (cl ^ (((rl >> 2) & 7) << 4))] = f2bf(s);
                }
            }
        }
    } else {                             // IG waves: p = sigm(ig+b), fixed-point
#pragma unroll
        for (int j = 0; j < 4; ++j) {
            const int colg = tN0 + wn_sub * 64 + j * 16 + cb;
            const int cl = wn_sub * 64 + j * 16 + cb;
            const float bj = b_in[colg];
#pragma unroll
            for (int i = 0; i < 8; ++i) {
                const int rl0 = wm * 128 + i * 16 + r0;
#pragma unroll
                for (int rr = 0; rr < 4; ++rr) {
                    const int rl = rl0 + rr;
                    float p = sigm(acc[i][j][rr] + bj);
                    lds[32768 + rl * 128 + (cl ^ (((rl >> 2) & 7) << 4))] =
                        (u16)(p * 65535.0f + 0.5f);
                }
            }
        }
    }
    asm volatile("s_waitcnt lgkmcnt(0)" ::: "memory");
    __builtin_amdgcn_s_barrier();
    __builtin_amdgcn_sched_barrier(0);

    // ---- epilogue stage 2: vectorized combine + 16B stores + chunk aggregates ----
    // thread -> col-chunk cc (8 cols), rows rg0..rg0+7 (full 256x128 tile).
    // Aacc/Bacc: per-column 8-row segment aggregates (t-ascending, f32), from
    // the SAME quantized bf16 s / bf16 xb values scan_pass1 consumed.
    const int cc = tid & 15;
    const int rg0 = (tid >> 4) * 8;
    float Aacc[8] = {1.f, 1.f, 1.f, 1.f, 1.f, 1.f, 1.f, 1.f};
    float Bacc[8] = {};
#pragma unroll
    for (int k = 0; k < 8; ++k) {
        const int rl = rg0 + k;
        const int ch = (cc ^ (((rl >> 2) & 7) << 1)) * 8;   // swizzled chunk base
        short8 sv = *(const short8*)&lds[rl * 128 + ch];
        short8 pv = *(const short8*)&lds[32768 + rl * 128 + ch];
        const size_t go = (size_t)(tM0 + rl) * DDIM + tN0 + cc * 8;
        short8 xv = *(const short8*)&X[go];
        short8 ov;
#pragma unroll
        for (int e = 0; e < 8; ++e) {
            float s = bf_u16((u16)sv[e]);
            float p = (float)((u16)pv[e]) * (1.0f / 65535.0f);
            float xf = bf_u16((u16)xv[e]);
            float be = sqrtf(1.0f - __expf(2.0f * s) + 1e-6f);
            u16 xbq = f2bf(be * p * xf);
            ov[e] = (short)xbq;
            float a = __expf(s);
            Bacc[e] = fmaf(a, Bacc[e], bf_u16(xbq));
            Aacc[e] *= a;
        }
        *(short8*)&Sg[go] = sv;
        *(short8*)&XBg[go] = ov;
    }

    // ---- fused scan_pass1: combine 8-row segments into 64-row chunk aggs ----
    asm volatile("s_waitcnt lgkmcnt(0)" ::: "memory");
    __builtin_amdgcn_s_barrier();       // all S/P-region reads done -> reuse
    {
        float* fA = (float*)lds;        // [32 segs][128 cols]
        float* fB = (float*)lds + 4096; // [32 segs][128 cols]
        const int seg = tid >> 4;       // 0..31 (8 rows each)
#pragma unroll
        for (int e = 0; e < 8; ++e) {
            fA[seg * 128 + cc * 8 + e] = Aacc[e];
            fB[seg * 128 + cc * 8 + e] = Bacc[e];
        }
        asm volatile("s_waitcnt lgkmcnt(0)" ::: "memory");
        __builtin_amdgcn_s_barrier();
        const int chk = tid >> 7;       // 0..3 chunk within tile
        const int col = tid & 127;
        float A = 1.0f, Bv = 0.0f;
#pragma unroll
        for (int k = 0; k < 8; ++k) {   // t-ascending segment combine
            float a = fA[(chk * 8 + k) * 128 + col];
            float b = fB[(chk * 8 + k) * 128 + col];
            Bv = fmaf(a, Bv, b);
            A *= a;
        }
        const int bq = tM0 >> 13;                      // batch
        const int cw = ((tM0 & 8191) >> 6) + chk;      // chunk within batch
        const size_t gi = (size_t)cw * CHAINS + bq * DDIM + tN0 + col;
        AggA[gi] = A;
        AggB[gi] = Bv;
    }
}

// ---------- K4: pass2 — serial scan over NC chunk aggregates per chain ----------
__global__ __launch_bounds__(256)
void scan_pass2(const float* __restrict__ AggA, const float* __restrict__ AggB,
                float* __restrict__ H0) {
    const int chain = blockIdx.x * 256 + threadIdx.x;   // 4096 chains
    float p = 0.0f;
#pragma unroll 8
    for (int c = 0; c < NC; c++) {
        H0[(size_t)c * CHAINS + chain] = p;
        p = AggA[(size_t)c * CHAINS + chain] * p + AggB[(size_t)c * CHAINS + chain];
    }
}

// ---------- K5: pass3 — apply chunk prefix, write h (4-wide per thread) ----------
__global__ __launch_bounds__(256)
void scan_pass3(const u16* __restrict__ S, const u16* __restrict__ XB,
                const float* __restrict__ H0, float* __restrict__ out) {
    const int c = blockIdx.x, bq = blockIdx.z;
    const int d0 = threadIdx.x * 4;
    size_t base = ((size_t)(bq * T_SEQ + c * CHUNK)) * DDIM + d0;
    const int chain = bq * DDIM + d0;

    float4 h = *(const float4*)(H0 + (size_t)c * CHAINS + chain);
#pragma unroll 4
    for (int t = 0; t < CHUNK; t++) {
        ushort4 sp = *(const ushort4*)(S + base);
        ushort4 xp = *(const ushort4*)(XB + base);
        h.x = fmaf(__expf(bf_u16(sp.x)), h.x, bf_u16(xp.x));
        h.y = fmaf(__expf(bf_u16(sp.y)), h.y, bf_u16(xp.y));
        h.z = fmaf(__expf(bf_u16(sp.z)), h.z, bf_u16(xp.z));
        h.w = fmaf(__expf(bf_u16(sp.w)), h.w, bf_u16(xp.w));
        *(float4*)(out + base) = h;
        base += DDIM;
    }
}

// ---------- launch ----------
extern "C" void kernel_launch(void* const* d_in, const int* in_sizes, int n_in,
                              void* d_out, int out_size, void* d_ws, size_t ws_size,
                              hipStream_t stream) {
    const float* x   = (const float*)d_in[0];
    const float* Win = (const float*)d_in[1];
    const float* bin = (const float*)d_in[2];
    const float* Wg  = (const float*)d_in[3];
    const float* bg  = (const float*)d_in[4];
    const float* lam = (const float*)d_in[5];
    float* out = (float*)d_out;

    // ws layout (MiB): Wi_bf 0..2, Wg_bf 2..4, S 4..68, XB 68..132,
    // AggA 132..134, AggB 134..136, H0 136..138  (= 138 MiB)
    char* w = (char*)d_ws;
    u16* Wi_bf  = (u16*)(w);
    u16* Wg_bf  = (u16*)(w + (size_t)(2) * 1024 * 1024);
    u16* Sg     = (u16*)(w + (size_t)(4) * 1024 * 1024);
    u16* XBg    = (u16*)(w + (size_t)(68) * 1024 * 1024);
    float* AggA = (float*)(w + (size_t)(132) * 1024 * 1024);
    float* AggB = (float*)(w + (size_t)(134) * 1024 * 1024);
    float* H0   = (float*)(w + (size_t)(136) * 1024 * 1024);

    // x_bf16 staged in first 64 MiB of d_out (read by GEMM main loop AND
    // epilogue; dead after GEMM; pass3 then overwrites d_out with h)
    u16* Xbf = (u16*)d_out;

    // K1: one fused convert (x + both W)
    cvt_all<<<dim3((N4X + 2 * N4W) / 256), dim3(256), 0, stream>>>(
        x, Win, Wg, Xbf, Wi_bf, Wg_bf);

    // K2: fused gate GEMM + gating epilogue + fused scan_pass1
    gemm_fused<<<dim3((DDIM / 128) * (MM / 256)), dim3(512), 0, stream>>>(
        Xbf, Wi_bf, Wg_bf, bin, bg, lam, Sg, XBg, AggA, AggB);

    // K4-K5: chunk-prefix scan + apply
    scan_pass2<<<dim3(CHAINS / 256), dim3(256), 0, stream>>>(AggA, AggB, H0);
    scan_pass3<<<dim3(NC, 1, BB), dim3(256), 0, stream>>>(Sg, XBg, H0, out);
}

// Round 8
// 452.009 us; speedup vs baseline: 1.1127x; 1.0210x over previous
//
#include <hip/hip_runtime.h>

typedef unsigned short u16;
typedef __attribute__((ext_vector_type(8))) short short8;   // 8 bf16 = 4 VGPRs (MFMA A/B frag)
typedef __attribute__((ext_vector_type(4))) float f32x4;    // MFMA C/D frag

#define T_SEQ 8192
#define DDIM 1024
#define BB 4
#define MM (BB * T_SEQ)      // 32768
#define NC 128               // chunks along T
#define CHUNK (T_SEQ / NC)   // 64
#define CHAINS (BB * DDIM)   // 4096

// ---------- helpers ----------
__device__ __forceinline__ float bf_lo(unsigned p) {
    union { unsigned u; float f; } v; v.u = p << 16; return v.f;
}
__device__ __forceinline__ float bf_hi(unsigned p) {
    union { unsigned u; float f; } v; v.u = p & 0xffff0000u; return v.f;
}
__device__ __forceinline__ float bf_u16(u16 p) {
    union { unsigned u; float f; } v; v.u = ((unsigned)p) << 16; return v.f;
}
__device__ __forceinline__ u16 f2bf(float f) {
    union { unsigned u; float f; } v; v.f = f;
    unsigned r = v.u + 0x7fffu + ((v.u >> 16) & 1u);   // RNE
    return (u16)(r >> 16);
}
__device__ __forceinline__ float sigm(float z) {
    return __builtin_amdgcn_rcpf(1.0f + __expf(-z));
}
__device__ __forceinline__ void gld16(const u16* g, u16* l) {
    __builtin_amdgcn_global_load_lds((const __attribute__((address_space(1))) void*)g,
                                     (__attribute__((address_space(3))) void*)l, 16, 0, 0);
}

// ---------- K1: fused fp32 -> bf16 convert for x, W_in, W_gate ----------
#define N4X (MM * DDIM / 4)      // 8388608 float4s
#define N4W (DDIM * DDIM / 4)    // 262144 float4s
__global__ __launch_bounds__(256) void cvt_all(const float* __restrict__ x,
                                               const float* __restrict__ Wi,
                                               const float* __restrict__ Wg,
                                               u16* __restrict__ Xb,
                                               u16* __restrict__ Wib,
                                               u16* __restrict__ Wgb) {
    int i = blockIdx.x * 256 + threadIdx.x;   // global float4 index
    const float* src; u16* dst; int j;
    if (i < N4X)            { src = x;  dst = Xb;  j = i; }
    else if (i < N4X + N4W) { src = Wi; dst = Wib; j = i - N4X; }
    else                    { src = Wg; dst = Wgb; j = i - N4X - N4W; }
    float4 v = ((const float4*)src)[j];
    ushort4 o;
    o.x = f2bf(v.x); o.y = f2bf(v.y); o.z = f2bf(v.z); o.w = f2bf(v.w);
    ((ushort4*)dst)[j] = o;
}

// ---------- K2: fused bf16 GEMM + gating epilogue + fused scan_pass1 ----------
// R7 post-mortem: total = gemm + ~272us fixed floor -> gemm is the only lever.
// Four 1-block/CU schedules all pinned at 30-33% MfmaUtil: with one workgroup
// per CU, every barrier drain stalls the WHOLE CU. This round: 2 co-resident
// blocks/CU (m114: independent blocks co-schedule MFMA freely; one block's
// barrier bubble is filled by the other). Block = 256 thr / 4 waves, tile
// 128 x (128 cols x 2 gates), wave-tile 64x128 (acc[4][8]); LDS = ring-3 of
// K=32 slots, 72 KB -> 144 KB/CU = 2 blocks. Read ratio per wave unchanged
// vs R4 (12KB/K32) -> single variable = co-residency. Phases mirror R4:
// P1 {8 ds_read; 3 gld; bar; lgkmcnt0; 16 MFMA; bar}, P2 {4 ds_read; 3 gld;
// vmcnt(6) cert slot h+1; bar; lgkmcnt0; 16 MFMA; bar}. 6 staging rounds per
// slot; steady outstanding 12 -> vmcnt(6); tail cert vmcnt(0) at pair 30.

#define MROWJ(i_, av, J)                                                                     \
    acc[i_][(J)+0] = __builtin_amdgcn_mfma_f32_16x16x32_bf16(av, b0, acc[i_][(J)+0], 0,0,0); \
    acc[i_][(J)+1] = __builtin_amdgcn_mfma_f32_16x16x32_bf16(av, b1, acc[i_][(J)+1], 0,0,0); \
    acc[i_][(J)+2] = __builtin_amdgcn_mfma_f32_16x16x32_bf16(av, b2, acc[i_][(J)+2], 0,0,0); \
    acc[i_][(J)+3] = __builtin_amdgcn_mfma_f32_16x16x32_bf16(av, b3, acc[i_][(J)+3], 0,0,0);

#define MQUADJ(J) MROWJ(0, a0, J) MROWJ(1, a1, J) MROWJ(2, a2, J) MROWJ(3, a3, J)

// reads (swizzled) from compile-time ring slot s_ (A: 128 rows x 32; B: 256 x 32)
#define LDA_S(s_, i) (*(const short8*)&lds[(s_)*4096 + (arow0 + (i)*16)*32 + aoff])
#define LDB_S(s_, j) (*(const short8*)&lds[12288 + (s_)*8192 + (brow0 + (j)*16)*32 + aoff])

// staging rounds (64 rows x 4KB each): A rb=0..1, B rb=0..3 (Wi 0-1, Wg 2-3)
#define STA_R(s_, ht_, rb) gld16(gA + (size_t)(ht_)*32 + (size_t)(rb)*64*DDIM,               \
                                 &lds[(s_)*4096 + (rb)*2048 + tid*8])
#define STB_R(s_, ht_, rb) gld16(((rb) < 2 ? gBi + (size_t)(rb)*64*DDIM                      \
                                           : gBg + (size_t)((rb)-2)*64*DDIM)                 \
                                     + (size_t)(ht_)*32,                                     \
                                 &lds[12288 + (s_)*8192 + (rb)*2048 + tid*8])

#define PAIRX(s_, ss_, ht_, DOST, VMS)                                                       \
    /* P1: cols 0-3 */                                                                       \
    b0 = LDB_S(s_, 0); b1 = LDB_S(s_, 1); b2 = LDB_S(s_, 2); b3 = LDB_S(s_, 3);              \
    a0 = LDA_S(s_, 0); a1 = LDA_S(s_, 1); a2 = LDA_S(s_, 2); a3 = LDA_S(s_, 3);              \
    if (DOST) { STA_R(ss_, ht_, 0); STA_R(ss_, ht_, 1); STB_R(ss_, ht_, 0); }                \
    __builtin_amdgcn_s_barrier();                                                            \
    asm volatile("s_waitcnt lgkmcnt(0)" ::: "memory");                                       \
    __builtin_amdgcn_sched_barrier(0);                                                       \
    __builtin_amdgcn_s_setprio(1);                                                           \
    MQUADJ(0)                                                                                \
    __builtin_amdgcn_s_setprio(0);                                                           \
    __builtin_amdgcn_s_barrier();                                                            \
    /* P2: cols 4-7 */                                                                       \
    b0 = LDB_S(s_, 4); b1 = LDB_S(s_, 5); b2 = LDB_S(s_, 6); b3 = LDB_S(s_, 7);              \
    if (DOST) { STB_R(ss_, ht_, 1); STB_R(ss_, ht_, 2); STB_R(ss_, ht_, 3); }                \
    asm volatile("s_waitcnt " VMS ::: "memory");                                             \
    __builtin_amdgcn_s_barrier();                                                            \
    asm volatile("s_waitcnt lgkmcnt(0)" ::: "memory");                                       \
    __builtin_amdgcn_sched_barrier(0);                                                       \
    __builtin_amdgcn_s_setprio(1);                                                           \
    MQUADJ(4)                                                                                \
    __builtin_amdgcn_s_setprio(0);                                                           \
    __builtin_amdgcn_s_barrier();

__global__ __launch_bounds__(256, 2)
void gemm_fused(const u16* __restrict__ X, const u16* __restrict__ Wi,
                const u16* __restrict__ Wg, const float* __restrict__ b_in,
                const float* __restrict__ b_gate, const float* __restrict__ lam,
                u16* __restrict__ Sg, u16* __restrict__ XBg,
                float* __restrict__ AggA, float* __restrict__ AggB) {
    const int bid = blockIdx.x;         // 0..2047
    const int xcd = bid & 7;
    const int r = bid >> 3;             // 0..255
    const int n_tile = r & 7;           // N fastest within an XCD
    const int m_tile = xcd * 32 + (r >> 3);   // 0..255
    const int tN0 = n_tile * 128;
    const int tM0 = m_tile * 128;

    const int tid = threadIdx.x;        // 0..255
    const int lane = tid & 63;
    const int w = tid >> 6;             // 0..3
    const int wm = w & 1;               // M half (rows 0-63 / 64-127)
    const int gate = w >> 1;            // 0: IG (Wi), 1: RG (Wg)

    __shared__ u16 lds[36864];          // 72KB: A ring [0,12288), B ring [12288,36864)

    // staging source pointers (per-thread, pre-swizzled column chunk)
    const int srow = tid >> 2;                          // 0..63
    const int c8log = (tid & 3) ^ ((tid >> 3) & 3);     // inverse swizzle on source
    const u16* gA  = X  + (size_t)(tM0 + srow) * DDIM + c8log * 8;
    const u16* gBi = Wi + (size_t)(tN0 + srow) * DDIM + c8log * 8;
    const u16* gBg = Wg + (size_t)(tN0 + srow) * DDIM + c8log * 8;

    // read-side constants
    const int lm = lane & 15;
    const int aoff = (((lane >> 4) ^ ((lm >> 1) & 3))) * 8;  // swizzled chunk, lane-only
    const int arow0 = wm * 64 + lm;                  // + i*16, i 0..3
    const int brow0 = gate * 128 + lm;               // + j*16, j 0..7

    f32x4 acc[4][8] = {};
    short8 a0, a1, a2, a3, b0, b1, b2, b3;

    // ---- prologue: stage ht0->slot0, ht1->slot1 (12 rounds); certify slot 0 ----
    STA_R(0, 0, 0); STA_R(0, 0, 1); STB_R(0, 0, 0); STB_R(0, 0, 1); STB_R(0, 0, 2); STB_R(0, 0, 3);
    STA_R(1, 1, 0); STA_R(1, 1, 1); STB_R(1, 1, 0); STB_R(1, 1, 1); STB_R(1, 1, 2); STB_R(1, 1, 3);
    asm volatile("s_waitcnt vmcnt(6)" ::: "memory");   // slot 0 landed
    __builtin_amdgcn_s_barrier();

    // ---- main loop: pairs h=3g..3g+2 compute slot h%3, stage ht h+2 ----
    for (int g = 0; g < 10; ++g) {
        const int hb = 3 * g;
        PAIRX(0, 2, hb + 2, 1, "vmcnt(6)")
        PAIRX(1, 0, hb + 3, 1, "vmcnt(6)")
        PAIRX(2, 1, hb + 4, 1, "vmcnt(6)")
    }
    // ---- tail: pair 30 (cert ht31 via drain), pair 31 ----
    PAIRX(0, 0, 0, 0, "vmcnt(0)")
    PAIRX(1, 0, 0, 0, "vmcnt(0)")
    // last PAIRX ends with barrier; all slot reads drained -> LDS reusable

    // ---- epilogue stage 1: dump per-acc values to LDS (XOR bank swizzle) ----
    // C/D layout: col=lane&15, row=(lane>>4)*4+rr. Local tile 128x128.
    // S region  lds[0,16384):      s  (bf16, == value the scan consumes)
    // P region  lds[16384,32768):  p  (u16 fixed-point /65535 -> err ~1e-5)
    const int r0 = (lane >> 4) << 2;
    const int cb = lane & 15;
    if (gate) {                          // RG waves: s = nsp*sigm(rg+b)
#pragma unroll
        for (int j = 0; j < 8; ++j) {
            const int colg = tN0 + j * 16 + cb;
            const int cl = j * 16 + cb;
            const float bj = b_gate[colg];
            const float nsp = -8.0f * log1pf(__expf(lam[colg]));
#pragma unroll
            for (int i = 0; i < 4; ++i) {
                const int rl0 = wm * 64 + i * 16 + r0;
#pragma unroll
                for (int rr = 0; rr < 4; ++rr) {
                    const int rl = rl0 + rr;
                    float s = nsp * sigm(acc[i][j][rr] + bj);
                    lds[rl * 128 + (cl ^ (((rl >> 2) & 7) << 4))] = f2bf(s);
                }
            }
        }
    } else {                             // IG waves: p = sigm(ig+b), fixed-point
#pragma unroll
        for (int j = 0; j < 8; ++j) {
            const int colg = tN0 + j * 16 + cb;
            const int cl = j * 16 + cb;
            const float bj = b_in[colg];
#pragma unroll
            for (int i = 0; i < 4; ++i) {
                const int rl0 = wm * 64 + i * 16 + r0;
#pragma unroll
                for (int rr = 0; rr < 4; ++rr) {
                    const int rl = rl0 + rr;
                    float p = sigm(acc[i][j][rr] + bj);
                    lds[16384 + rl * 128 + (cl ^ (((rl >> 2) & 7) << 4))] =
                        (u16)(p * 65535.0f + 0.5f);
                }
            }
        }
    }
    asm volatile("s_waitcnt lgkmcnt(0)" ::: "memory");
    __builtin_amdgcn_s_barrier();
    __builtin_amdgcn_sched_barrier(0);

    // ---- epilogue stage 2: vectorized combine + 16B stores + chunk aggregates ----
    // thread -> col-chunk cc (8 cols), rows rg0..rg0+7 (full 128x128 tile).
    const int cc = tid & 15;
    const int rg0 = (tid >> 4) * 8;
    float Aacc[8] = {1.f, 1.f, 1.f, 1.f, 1.f, 1.f, 1.f, 1.f};
    float Bacc[8] = {};
#pragma unroll
    for (int k = 0; k < 8; ++k) {
        const int rl = rg0 + k;
        const int ch = (cc ^ (((rl >> 2) & 7) << 1)) * 8;   // swizzled chunk base
        short8 sv = *(const short8*)&lds[rl * 128 + ch];
        short8 pv = *(const short8*)&lds[16384 + rl * 128 + ch];
        const size_t go = (size_t)(tM0 + rl) * DDIM + tN0 + cc * 8;
        short8 xv = *(const short8*)&X[go];
        short8 ov;
#pragma unroll
        for (int e = 0; e < 8; ++e) {
            float s = bf_u16((u16)sv[e]);
            float p = (float)((u16)pv[e]) * (1.0f / 65535.0f);
            float xf = bf_u16((u16)xv[e]);
            float be = sqrtf(1.0f - __expf(2.0f * s) + 1e-6f);
            u16 xbq = f2bf(be * p * xf);
            ov[e] = (short)xbq;
            float a = __expf(s);
            Bacc[e] = fmaf(a, Bacc[e], bf_u16(xbq));
            Aacc[e] *= a;
        }
        *(short8*)&Sg[go] = sv;
        *(short8*)&XBg[go] = ov;
    }

    // ---- fused scan_pass1: combine 8-row segments into 64-row chunk aggs ----
    asm volatile("s_waitcnt lgkmcnt(0)" ::: "memory");
    __builtin_amdgcn_s_barrier();       // all S/P-region reads done -> reuse
    {
        float* fA = (float*)lds;        // [16 segs][128 cols]
        float* fB = (float*)lds + 2048; // [16 segs][128 cols]
        const int seg = tid >> 4;       // 0..15 (8 rows each)
#pragma unroll
        for (int e = 0; e < 8; ++e) {
            fA[seg * 128 + cc * 8 + e] = Aacc[e];
            fB[seg * 128 + cc * 8 + e] = Bacc[e];
        }
        asm volatile("s_waitcnt lgkmcnt(0)" ::: "memory");
        __builtin_amdgcn_s_barrier();
        const int chk = tid >> 7;       // 0..1 chunk within tile
        const int col = tid & 127;
        float A = 1.0f, Bv = 0.0f;
#pragma unroll
        for (int k = 0; k < 8; ++k) {   // t-ascending segment combine
            float a = fA[(chk * 8 + k) * 128 + col];
            float b = fB[(chk * 8 + k) * 128 + col];
            Bv = fmaf(a, Bv, b);
            A *= a;
        }
        const int bq = tM0 >> 13;                      // batch
        const int cw = ((tM0 & 8191) >> 6) + chk;      // chunk within batch
        const size_t gi = (size_t)cw * CHAINS + bq * DDIM + tN0 + col;
        AggA[gi] = A;
        AggB[gi] = Bv;
    }
}

// ---------- K4: pass2 — serial scan over NC chunk aggregates per chain ----------
__global__ __launch_bounds__(256)
void scan_pass2(const float* __restrict__ AggA, const float* __restrict__ AggB,
                float* __restrict__ H0) {
    const int chain = blockIdx.x * 256 + threadIdx.x;   // 4096 chains
    float p = 0.0f;
#pragma unroll 8
    for (int c = 0; c < NC; c++) {
        H0[(size_t)c * CHAINS + chain] = p;
        p = AggA[(size_t)c * CHAINS + chain] * p + AggB[(size_t)c * CHAINS + chain];
    }
}

// ---------- K5: pass3 — apply chunk prefix, write h (4-wide per thread) ----------
__global__ __launch_bounds__(256)
void scan_pass3(const u16* __restrict__ S, const u16* __restrict__ XB,
                const float* __restrict__ H0, float* __restrict__ out) {
    const int c = blockIdx.x, bq = blockIdx.z;
    const int d0 = threadIdx.x * 4;
    size_t base = ((size_t)(bq * T_SEQ + c * CHUNK)) * DDIM + d0;
    const int chain = bq * DDIM + d0;

    float4 h = *(const float4*)(H0 + (size_t)c * CHAINS + chain);
#pragma unroll 4
    for (int t = 0; t < CHUNK; t++) {
        ushort4 sp = *(const ushort4*)(S + base);
        ushort4 xp = *(const ushort4*)(XB + base);
        h.x = fmaf(__expf(bf_u16(sp.x)), h.x, bf_u16(xp.x));
        h.y = fmaf(__expf(bf_u16(sp.y)), h.y, bf_u16(xp.y));
        h.z = fmaf(__expf(bf_u16(sp.z)), h.z, bf_u16(xp.z));
        h.w = fmaf(__expf(bf_u16(sp.w)), h.w, bf_u16(xp.w));
        *(float4*)(out + base) = h;
        base += DDIM;
    }
}

// ---------- launch ----------
extern "C" void kernel_launch(void* const* d_in, const int* in_sizes, int n_in,
                              void* d_out, int out_size, void* d_ws, size_t ws_size,
                              hipStream_t stream) {
    const float* x   = (const float*)d_in[0];
    const float* Win = (const float*)d_in[1];
    const float* bin = (const float*)d_in[2];
    const float* Wg  = (const float*)d_in[3];
    const float* bg  = (const float*)d_in[4];
    const float* lam = (const float*)d_in[5];
    float* out = (float*)d_out;

    // ws layout (MiB): Wi_bf 0..2, Wg_bf 2..4, S 4..68, XB 68..132,
    // AggA 132..134, AggB 134..136, H0 136..138  (= 138 MiB)
    char* w = (char*)d_ws;
    u16* Wi_bf  = (u16*)(w);
    u16* Wg_bf  = (u16*)(w + (size_t)(2) * 1024 * 1024);
    u16* Sg     = (u16*)(w + (size_t)(4) * 1024 * 1024);
    u16* XBg    = (u16*)(w + (size_t)(68) * 1024 * 1024);
    float* AggA = (float*)(w + (size_t)(132) * 1024 * 1024);
    float* AggB = (float*)(w + (size_t)(134) * 1024 * 1024);
    float* H0   = (float*)(w + (size_t)(136) * 1024 * 1024);

    // x_bf16 staged in first 64 MiB of d_out (read by GEMM main loop AND
    // epilogue; dead after GEMM; pass3 then overwrites d_out with h)
    u16* Xbf = (u16*)d_out;

    // K1: one fused convert (x + both W)
    cvt_all<<<dim3((N4X + 2 * N4W) / 256), dim3(256), 0, stream>>>(
        x, Win, Wg, Xbf, Wi_bf, Wg_bf);

    // K2: fused gate GEMM + epilogue + pass1, 2-blocks/CU TLP geometry
    gemm_fused<<<dim3((DDIM / 128) * (MM / 128)), dim3(256), 0, stream>>>(
        Xbf, Wi_bf, Wg_bf, bin, bg, lam, Sg, XBg, AggA, AggB);

    // K4-K5: chunk-prefix scan + apply
    scan_pass2<<<dim3(CHAINS / 256), dim3(256), 0, stream>>>(AggA, AggB, H0);
    scan_pass3<<<dim3(NC, 1, BB), dim3(256), 0, stream>>>(Sg, XBg, H0, out);
}